// Round 1
// baseline (479.564 us; speedup 1.0000x reference)
//
#include <hip/hip_runtime.h>
#include <hip/hip_bf16.h>
#include <math.h>

#define N_NODES 20000
#define N_EDGES 320000
#define EP (N_EDGES + N_NODES)   // edges + self loops = 340000
#define F_IN 256
#define NHID 64
#define H1 8
#define D1 (H1 * NHID)           // 512
#define NCLS 40
#define NEG_SLOPE 0.2f

__device__ __forceinline__ float wave_max(float v) {
#pragma unroll
  for (int o = 32; o > 0; o >>= 1) v = fmaxf(v, __shfl_xor(v, o));
  return v;
}
__device__ __forceinline__ float wave_sum(float v) {
#pragma unroll
  for (int o = 32; o > 0; o >>= 1) v += __shfl_xor(v, o);
  return v;
}

// ---------------- CSR build ----------------
__global__ void count_deg(const int* __restrict__ ei, int* __restrict__ deg) {
  int e = blockIdx.x * blockDim.x + threadIdx.x;
  if (e >= EP) return;
  int dst = (e < N_EDGES) ? ei[N_EDGES + e] : (e - N_EDGES);
  atomicAdd(&deg[dst], 1);
}

#define SCAN_T 256
#define SCAN_CHUNK 79  // 256*79 = 20224 >= 20000
__global__ void scan_kernel(const int* __restrict__ deg, int* __restrict__ offsets) {
  __shared__ int sums[SCAN_T];
  int t = threadIdx.x;
  int lo = t * SCAN_CHUNK;
  int hi = min(lo + SCAN_CHUNK, N_NODES);
  int s = 0;
  for (int i = lo; i < hi; ++i) s += deg[i];
  sums[t] = s;
  __syncthreads();
  if (t == 0) {
    int run = 0;
    for (int i = 0; i < SCAN_T; ++i) { int v = sums[i]; sums[i] = run; run += v; }
  }
  __syncthreads();
  int run = sums[t];
  for (int i = lo; i < hi; ++i) { offsets[i] = run; run += deg[i]; }
  if (hi == N_NODES) offsets[N_NODES] = run;  // benign multi-write of same value
}

__global__ void scatter_edges(const int* __restrict__ ei, const int* __restrict__ offsets,
                              int* __restrict__ cursor, int* __restrict__ edge_src) {
  int e = blockIdx.x * blockDim.x + threadIdx.x;
  if (e >= EP) return;
  int src, dst;
  if (e < N_EDGES) { src = ei[e]; dst = ei[N_EDGES + e]; }
  else             { src = dst = e - N_EDGES; }
  int pos = offsets[dst] + atomicAdd(&cursor[dst], 1);
  edge_src[pos] = src;
}

// ---------------- GEMM1: h1 = x @ W1   [20000,256]x[256,512] ----------------
__global__ __launch_bounds__(256) void gemm1_kernel(const float* __restrict__ A,
                                                    const float* __restrict__ B,
                                                    float* __restrict__ C) {
  __shared__ float As[16][65];
  __shared__ float Bs[16][65];
  int tid = threadIdx.x;
  int bx = blockIdx.x & 7;        // 512/64 = 8 col blocks
  int by = blockIdx.x >> 3;
  int row0 = by * 64, col0 = bx * 64;
  int ty = tid >> 4, tx = tid & 15;
  int la_row = tid >> 2;          // 0..63
  int la_k = (tid & 3) * 4;       // 0,4,8,12
  int lb_k = tid >> 4;            // 0..15
  int lb_n = (tid & 15) * 4;      // 0..60
  float acc[4][4] = {};
  for (int k0 = 0; k0 < F_IN; k0 += 16) {
    int ar = row0 + la_row;
    float4 av = (ar < N_NODES) ? *(const float4*)&A[(size_t)ar * F_IN + k0 + la_k]
                               : make_float4(0.f, 0.f, 0.f, 0.f);
    As[la_k + 0][la_row] = av.x; As[la_k + 1][la_row] = av.y;
    As[la_k + 2][la_row] = av.z; As[la_k + 3][la_row] = av.w;
    float4 bv = *(const float4*)&B[(size_t)(k0 + lb_k) * D1 + col0 + lb_n];
    Bs[lb_k][lb_n + 0] = bv.x; Bs[lb_k][lb_n + 1] = bv.y;
    Bs[lb_k][lb_n + 2] = bv.z; Bs[lb_k][lb_n + 3] = bv.w;
    __syncthreads();
#pragma unroll
    for (int k = 0; k < 16; ++k) {
      float a[4], b[4];
#pragma unroll
      for (int i = 0; i < 4; ++i) a[i] = As[k][ty * 4 + i];
#pragma unroll
      for (int j = 0; j < 4; ++j) b[j] = Bs[k][tx * 4 + j];
#pragma unroll
      for (int i = 0; i < 4; ++i)
#pragma unroll
        for (int j = 0; j < 4; ++j) acc[i][j] += a[i] * b[j];
    }
    __syncthreads();
  }
#pragma unroll
  for (int i = 0; i < 4; ++i) {
    int r = row0 + ty * 4 + i;
    if (r < N_NODES)
      *(float4*)&C[(size_t)r * D1 + col0 + tx * 4] =
          make_float4(acc[i][0], acc[i][1], acc[i][2], acc[i][3]);
  }
}

// ---------------- alpha1: per-node attention logits ----------------
__global__ void alpha1_kernel(const float* __restrict__ h1,
                              const float* __restrict__ a_src, const float* __restrict__ a_dst,
                              float* __restrict__ asrc, float* __restrict__ adst) {
  int n = blockIdx.x;
  int lane = threadIdx.x;  // 64 threads
#pragma unroll
  for (int h = 0; h < H1; ++h) {
    float v = h1[(size_t)n * D1 + h * NHID + lane];
    float s1 = wave_sum(v * a_src[h * NHID + lane]);
    float s2 = wave_sum(v * a_dst[h * NHID + lane]);
    if (lane == 0) { asrc[n * H1 + h] = s1; adst[n * H1 + h] = s2; }
  }
}

// ---------------- agg1: segment softmax + aggregate + b1 + ELU ----------------
__global__ __launch_bounds__(512) void agg1_kernel(const int* __restrict__ offsets,
                                                   const int* __restrict__ edge_src,
                                                   const float* __restrict__ asrc,
                                                   const float* __restrict__ adst,
                                                   const float* __restrict__ h1,
                                                   const float* __restrict__ b1,
                                                   float* __restrict__ out1) {
  int n = blockIdx.x;
  int h = threadIdx.x >> 6;
  int lane = threadIdx.x & 63;
  int base = offsets[n];
  int deg = offsets[n + 1] - base;
  float adv = adst[n * H1 + h];
  float lmax = -INFINITY;
  for (int e = lane; e < deg; e += 64) {
    int s = edge_src[base + e];
    float ev = asrc[s * H1 + h] + adv;
    ev = ev > 0.f ? ev : NEG_SLOPE * ev;
    lmax = fmaxf(lmax, ev);
  }
  float m = wave_max(lmax);
  float lsum = 0.f;
  for (int e = lane; e < deg; e += 64) {
    int s = edge_src[base + e];
    float ev = asrc[s * H1 + h] + adv;
    ev = ev > 0.f ? ev : NEG_SLOPE * ev;
    lsum += __expf(ev - m);
  }
  float inv = 1.f / (wave_sum(lsum) + 1e-16f);
  float acc = 0.f;
  for (int e = 0; e < deg; ++e) {
    int s = edge_src[base + e];                       // broadcast
    float ev = asrc[s * H1 + h] + adv;                // broadcast
    ev = ev > 0.f ? ev : NEG_SLOPE * ev;
    float alpha = __expf(ev - m) * inv;
    acc += alpha * h1[(size_t)s * D1 + h * NHID + lane];  // coalesced 256B
  }
  float v = acc + b1[h * NHID + lane];
  out1[(size_t)n * D1 + h * NHID + lane] = v > 0.f ? v : (__expf(v) - 1.f);  // ELU
}

// ---------------- GEMM2: h2 = out1 @ W2  [20000,512]x[512,40] ----------------
__global__ __launch_bounds__(256) void gemm2_kernel(const float* __restrict__ A,
                                                    const float* __restrict__ B,
                                                    float* __restrict__ C) {
  __shared__ float As[32][33];
  __shared__ float Bs[32][41];
  int tid = threadIdx.x;
  int row0 = blockIdx.x * 32;
  int ty = tid >> 3;        // 0..31
  int tx = tid & 7;         // col group of 5
  float acc[5] = {};
  for (int k0 = 0; k0 < D1; k0 += 32) {
    int l = tid * 4;
    int am = l >> 5, ak = l & 31;
    int ar = row0 + am;
    float4 av = (ar < N_NODES) ? *(const float4*)&A[(size_t)ar * D1 + k0 + ak]
                               : make_float4(0.f, 0.f, 0.f, 0.f);
    As[ak + 0][am] = av.x; As[ak + 1][am] = av.y; As[ak + 2][am] = av.z; As[ak + 3][am] = av.w;
#pragma unroll
    for (int i = 0; i < 5; ++i) {
      int ll = tid * 5 + i;
      int bk = ll / NCLS, bn = ll % NCLS;
      Bs[bk][bn] = B[(size_t)(k0 + bk) * NCLS + bn];
    }
    __syncthreads();
#pragma unroll
    for (int k = 0; k < 32; ++k) {
      float a = As[k][ty];
#pragma unroll
      for (int j = 0; j < 5; ++j) acc[j] += a * Bs[k][tx * 5 + j];
    }
    __syncthreads();
  }
  int r = row0 + ty;
  if (r < N_NODES)
#pragma unroll
    for (int j = 0; j < 5; ++j) C[(size_t)r * NCLS + tx * 5 + j] = acc[j];
}

// ---------------- alpha2 ----------------
__global__ void alpha2_kernel(const float* __restrict__ h2,
                              const float* __restrict__ a_src, const float* __restrict__ a_dst,
                              float* __restrict__ asrc, float* __restrict__ adst) {
  int n = blockIdx.x;
  int lane = threadIdx.x;  // 64
  float v = (lane < NCLS) ? h2[(size_t)n * NCLS + lane] : 0.f;
  float s1 = wave_sum((lane < NCLS) ? v * a_src[lane] : 0.f);
  float s2 = wave_sum((lane < NCLS) ? v * a_dst[lane] : 0.f);
  if (lane == 0) { asrc[n] = s1; adst[n] = s2; }
}

// ---------------- agg2 + b2 + log_softmax -> d_out ----------------
__global__ __launch_bounds__(256) void agg2_kernel(const int* __restrict__ offsets,
                                                   const int* __restrict__ edge_src,
                                                   const float* __restrict__ asrc,
                                                   const float* __restrict__ adst,
                                                   const float* __restrict__ h2,
                                                   const float* __restrict__ b2,
                                                   float* __restrict__ out) {
  int n = (blockIdx.x * blockDim.x + threadIdx.x) >> 6;
  int lane = threadIdx.x & 63;
  if (n >= N_NODES) return;
  int base = offsets[n];
  int deg = offsets[n + 1] - base;
  float adv = adst[n];
  float lmax = -INFINITY;
  for (int e = lane; e < deg; e += 64) {
    int s = edge_src[base + e];
    float ev = asrc[s] + adv;
    ev = ev > 0.f ? ev : NEG_SLOPE * ev;
    lmax = fmaxf(lmax, ev);
  }
  float m = wave_max(lmax);
  float lsum = 0.f;
  for (int e = lane; e < deg; e += 64) {
    int s = edge_src[base + e];
    float ev = asrc[s] + adv;
    ev = ev > 0.f ? ev : NEG_SLOPE * ev;
    lsum += __expf(ev - m);
  }
  float inv = 1.f / (wave_sum(lsum) + 1e-16f);
  float acc = 0.f;
  for (int e = 0; e < deg; ++e) {
    int s = edge_src[base + e];
    float ev = asrc[s] + adv;
    ev = ev > 0.f ? ev : NEG_SLOPE * ev;
    float alpha = __expf(ev - m) * inv;
    if (lane < NCLS) acc += alpha * h2[(size_t)s * NCLS + lane];
  }
  float v = (lane < NCLS) ? acc + b2[lane] : -INFINITY;
  float m2 = wave_max(v);
  float se = wave_sum((lane < NCLS) ? __expf(v - m2) : 0.f);
  if (lane < NCLS) out[(size_t)n * NCLS + lane] = v - m2 - logf(se);
}

extern "C" void kernel_launch(void* const* d_in, const int* in_sizes, int n_in,
                              void* d_out, int out_size, void* d_ws, size_t ws_size,
                              hipStream_t stream) {
  const float* x   = (const float*)d_in[0];
  const int*   ei  = (const int*)d_in[1];
  const float* W1  = (const float*)d_in[2];
  const float* as1 = (const float*)d_in[3];
  const float* ad1 = (const float*)d_in[4];
  const float* b1  = (const float*)d_in[5];
  const float* W2  = (const float*)d_in[6];
  const float* as2 = (const float*)d_in[7];
  const float* ad2 = (const float*)d_in[8];
  const float* b2  = (const float*)d_in[9];
  float* out = (float*)d_out;

  char* ws = (char*)d_ws;
  size_t off = 0;
  auto alloc = [&](size_t bytes) -> char* {
    char* p = ws + off;
    off += (bytes + 255) & ~(size_t)255;
    return p;
  };
  int* deg      = (int*)alloc((size_t)N_NODES * 4);
  int* cursor   = (int*)alloc((size_t)N_NODES * 4);
  int* offsets  = (int*)alloc((size_t)(N_NODES + 1) * 4);
  int* edge_src = (int*)alloc((size_t)EP * 4);
  float* h1     = (float*)alloc((size_t)N_NODES * D1 * 4);
  float* out1   = (float*)alloc((size_t)N_NODES * D1 * 4);
  float* asrc1  = (float*)alloc((size_t)N_NODES * H1 * 4);
  float* adst1  = (float*)alloc((size_t)N_NODES * H1 * 4);
  float* h2     = (float*)alloc((size_t)N_NODES * NCLS * 4);
  float* asrc2  = (float*)alloc((size_t)N_NODES * 4);
  float* adst2  = (float*)alloc((size_t)N_NODES * 4);

  hipMemsetAsync(deg, 0, (size_t)N_NODES * 4, stream);
  hipMemsetAsync(cursor, 0, (size_t)N_NODES * 4, stream);

  count_deg<<<(EP + 255) / 256, 256, 0, stream>>>(ei, deg);
  scan_kernel<<<1, SCAN_T, 0, stream>>>(deg, offsets);
  scatter_edges<<<(EP + 255) / 256, 256, 0, stream>>>(ei, offsets, cursor, edge_src);

  gemm1_kernel<<<313 * 8, 256, 0, stream>>>(x, W1, h1);
  alpha1_kernel<<<N_NODES, 64, 0, stream>>>(h1, as1, ad1, asrc1, adst1);
  agg1_kernel<<<N_NODES, 512, 0, stream>>>(offsets, edge_src, asrc1, adst1, h1, b1, out1);

  gemm2_kernel<<<(N_NODES + 31) / 32, 256, 0, stream>>>(out1, W2, h2);
  alpha2_kernel<<<N_NODES, 64, 0, stream>>>(h2, as2, ad2, asrc2, adst2);
  agg2_kernel<<<(N_NODES * 64) / 256, 256, 0, stream>>>(offsets, edge_src, asrc2, adst2, h2, b2, out);
}

// Round 2
// 340.833 us; speedup vs baseline: 1.4070x; 1.4070x over previous
//
#include <hip/hip_runtime.h>
#include <hip/hip_bf16.h>
#include <math.h>

#define N_NODES 20000
#define N_EDGES 320000
#define EP (N_EDGES + N_NODES)   // 340000
#define F_IN 256
#define NHID 64
#define H1 8
#define D1 (H1 * NHID)           // 512
#define NCLS 40
#define NEG_SLOPE 0.2f
#define MAXD 64                  // LDS-cached edges per dst (deg ~Poisson(17); fallback handles >64)

__device__ __forceinline__ float wave_max(float v) {
#pragma unroll
  for (int o = 32; o > 0; o >>= 1) v = fmaxf(v, __shfl_xor(v, o));
  return v;
}
__device__ __forceinline__ float wave_sum(float v) {
#pragma unroll
  for (int o = 32; o > 0; o >>= 1) v += __shfl_xor(v, o);
  return v;
}
__device__ __forceinline__ float bf2f(unsigned short u) {
  union { unsigned int i; float f; } c; c.i = ((unsigned int)u) << 16; return c.f;
}
__device__ __forceinline__ unsigned short f2bf(float f) {
  union { float f; unsigned int i; } c; c.f = f;
  unsigned int x = c.i;
  return (unsigned short)((x + 0x7fffu + ((x >> 16) & 1u)) >> 16);  // RNE
}
__device__ __forceinline__ float lrelu(float x) { return x > 0.f ? x : NEG_SLOPE * x; }

// ---------------- CSR build ----------------
__global__ void count_deg(const int* __restrict__ ei, int* __restrict__ deg) {
  int e = blockIdx.x * blockDim.x + threadIdx.x;
  if (e >= EP) return;
  int dst = (e < N_EDGES) ? ei[N_EDGES + e] : (e - N_EDGES);
  atomicAdd(&deg[dst], 1);
}

#define SCAN_T 256
#define SCAN_CHUNK 79
__global__ void scan_kernel(const int* __restrict__ deg, int* __restrict__ offsets) {
  __shared__ int sums[SCAN_T];
  int t = threadIdx.x;
  int lo = t * SCAN_CHUNK;
  int hi = min(lo + SCAN_CHUNK, N_NODES);
  int s = 0;
  for (int i = lo; i < hi; ++i) s += deg[i];
  sums[t] = s;
  __syncthreads();
  if (t == 0) {
    int run = 0;
    for (int i = 0; i < SCAN_T; ++i) { int v = sums[i]; sums[i] = run; run += v; }
  }
  __syncthreads();
  int run = sums[t];
  for (int i = lo; i < hi; ++i) { offsets[i] = run; run += deg[i]; }
  if (hi == N_NODES) offsets[N_NODES] = run;
}

__global__ void scatter_edges(const int* __restrict__ ei, const int* __restrict__ offsets,
                              int* __restrict__ cursor, int* __restrict__ edge_src) {
  int e = blockIdx.x * blockDim.x + threadIdx.x;
  if (e >= EP) return;
  int src, dst;
  if (e < N_EDGES) { src = ei[e]; dst = ei[N_EDGES + e]; }
  else             { src = dst = e - N_EDGES; }
  int pos = offsets[dst] + atomicAdd(&cursor[dst], 1);
  edge_src[pos] = src;
}

// ---------------- GEMM1: h1 = x @ W1, fused alpha1, bf16 output ----------------
__global__ __launch_bounds__(256) void gemm1_kernel(const float* __restrict__ A,
                                                    const float* __restrict__ B,
                                                    const float* __restrict__ a_src,
                                                    const float* __restrict__ a_dst,
                                                    unsigned short* __restrict__ h1b,
                                                    float* __restrict__ asrc,
                                                    float* __restrict__ adst) {
  __shared__ float As[16][65];
  __shared__ float Bs[16][65];
  int tid = threadIdx.x;
  int bx = blockIdx.x & 7;        // head index (64-col block == one head)
  int by = blockIdx.x >> 3;
  int row0 = by * 64, col0 = bx * 64;
  int ty = tid >> 4, tx = tid & 15;
  int la_row = tid >> 2;
  int la_k = (tid & 3) * 4;
  int lb_k = tid >> 4;
  int lb_n = (tid & 15) * 4;
  float acc[4][4] = {};
  for (int k0 = 0; k0 < F_IN; k0 += 16) {
    int ar = row0 + la_row;
    float4 av = (ar < N_NODES) ? *(const float4*)&A[(size_t)ar * F_IN + k0 + la_k]
                               : make_float4(0.f, 0.f, 0.f, 0.f);
    As[la_k + 0][la_row] = av.x; As[la_k + 1][la_row] = av.y;
    As[la_k + 2][la_row] = av.z; As[la_k + 3][la_row] = av.w;
    float4 bv = *(const float4*)&B[(size_t)(k0 + lb_k) * D1 + col0 + lb_n];
    Bs[lb_k][lb_n + 0] = bv.x; Bs[lb_k][lb_n + 1] = bv.y;
    Bs[lb_k][lb_n + 2] = bv.z; Bs[lb_k][lb_n + 3] = bv.w;
    __syncthreads();
#pragma unroll
    for (int k = 0; k < 16; ++k) {
      float a[4], b[4];
#pragma unroll
      for (int i = 0; i < 4; ++i) a[i] = As[k][ty * 4 + i];
#pragma unroll
      for (int j = 0; j < 4; ++j) b[j] = Bs[k][tx * 4 + j];
#pragma unroll
      for (int i = 0; i < 4; ++i)
#pragma unroll
        for (int j = 0; j < 4; ++j) acc[i][j] += a[i] * b[j];
    }
    __syncthreads();
  }
  // epilogue: bf16 store + fused per-head attention logits
  float4 asv = *(const float4*)&a_src[bx * 64 + tx * 4];
  float4 adv = *(const float4*)&a_dst[bx * 64 + tx * 4];
#pragma unroll
  for (int i = 0; i < 4; ++i) {
    int r = row0 + ty * 4 + i;
    float ps = acc[i][0] * asv.x + acc[i][1] * asv.y + acc[i][2] * asv.z + acc[i][3] * asv.w;
    float pd = acc[i][0] * adv.x + acc[i][1] * adv.y + acc[i][2] * adv.z + acc[i][3] * adv.w;
#pragma unroll
    for (int o = 8; o > 0; o >>= 1) { ps += __shfl_xor(ps, o); pd += __shfl_xor(pd, o); }
    if (r < N_NODES) {
      ushort4 hv;
      hv.x = f2bf(acc[i][0]); hv.y = f2bf(acc[i][1]);
      hv.z = f2bf(acc[i][2]); hv.w = f2bf(acc[i][3]);
      *(ushort4*)&h1b[(size_t)r * D1 + col0 + tx * 4] = hv;
      if (tx == 0) { asrc[r * H1 + bx] = ps; adst[r * H1 + bx] = pd; }
    }
  }
}

// ---------------- agg1: LDS alpha + bf16 gather (2 edges/wave) + b1 + ELU ----------------
__global__ __launch_bounds__(512) void agg1_kernel(const int* __restrict__ offsets,
                                                   const int* __restrict__ edge_src,
                                                   const float* __restrict__ asrc,
                                                   const float* __restrict__ adst,
                                                   const unsigned short* __restrict__ h1b,
                                                   const float* __restrict__ b1,
                                                   float* __restrict__ out1) {
  __shared__ float lalpha[H1][MAXD + 2];
  __shared__ int   lsoff[MAXD + 2];
  int n = blockIdx.x;
  int h = threadIdx.x >> 6;
  int lane = threadIdx.x & 63;
  int base = offsets[n];
  int deg = offsets[n + 1] - base;
  int degc = min(deg, MAXD);

  // phase 0: src byte-offsets into LDS (bf16 row stride = 512*2 = 1024B)
  for (int e = (int)threadIdx.x; e < degc; e += 512) lsoff[e] = edge_src[base + e] << 10;
  if (threadIdx.x == 0 && (degc & 1)) lsoff[degc] = 0;
  __syncthreads();

  float advv = adst[n * H1 + h];
  // pass A: logits -> LDS, running max
  float m = -INFINITY;
  for (int e = lane; e < deg; e += 64) {
    int s = (e < MAXD) ? (lsoff[e] >> 10) : edge_src[base + e];
    float ev = lrelu(asrc[s * H1 + h] + advv);
    if (e < MAXD) lalpha[h][e] = ev;
    m = fmaxf(m, ev);
  }
  m = wave_max(m);
  // pass B: sum of exp
  float ssum = 0.f;
  for (int e = lane; e < deg; e += 64) {
    float ev;
    if (e < MAXD) ev = lalpha[h][e];
    else { int s = edge_src[base + e]; ev = lrelu(asrc[s * H1 + h] + advv); }
    ssum += __expf(ev - m);
  }
  float inv = 1.f / (wave_sum(ssum) + 1e-16f);
  // pass C: normalized alpha -> LDS
  for (int e = lane; e < degc; e += 64) lalpha[h][e] = __expf(lalpha[h][e] - m) * inv;
  if (lane == 0 && (degc & 1)) lalpha[h][degc] = 0.f;
  __syncthreads();

  // heavy loop: 2 edges per wave (lanes 0-31 = even slot, 32-63 = odd slot), 2 feats/lane
  int half = lane >> 5;
  int fl = lane & 31;
  const char* hb = (const char*)h1b + h * 128 + fl * 4;
  float ax = 0.f, ay = 0.f;
  int ngrp = (degc + 1) >> 1;
  for (int i = 0; i < ngrp; ++i) {
    int slot = 2 * i + half;
    float a = lalpha[h][slot];
    int so = lsoff[slot];
    unsigned int uv = *(const unsigned int*)(hb + so);
    ax += a * bf2f((unsigned short)(uv & 0xffffu));
    ay += a * bf2f((unsigned short)(uv >> 16));
  }
  // fallback (deg > MAXD), keeps same half-parity mapping
  for (int e = MAXD + half; e < deg; e += 2) {
    int s = edge_src[base + e];
    float a = __expf(lrelu(asrc[s * H1 + h] + advv) - m) * inv;
    unsigned int uv = *(const unsigned int*)(hb + ((size_t)s << 10));
    ax += a * bf2f((unsigned short)(uv & 0xffffu));
    ay += a * bf2f((unsigned short)(uv >> 16));
  }
  ax += __shfl_xor(ax, 32);
  ay += __shfl_xor(ay, 32);
  if (half == 0) {
    int c = h * NHID + fl * 2;
    float vx = ax + b1[c], vy = ay + b1[c + 1];
    vx = vx > 0.f ? vx : (__expf(vx) - 1.f);
    vy = vy > 0.f ? vy : (__expf(vy) - 1.f);
    *(float2*)&out1[(size_t)n * D1 + c] = make_float2(vx, vy);
  }
}

// ---------------- GEMM2: h2 = out1 @ W2, fused alpha2 ----------------
__global__ __launch_bounds__(256) void gemm2_kernel(const float* __restrict__ A,
                                                    const float* __restrict__ B,
                                                    const float* __restrict__ a_src,
                                                    const float* __restrict__ a_dst,
                                                    float* __restrict__ C,
                                                    float* __restrict__ asrc,
                                                    float* __restrict__ adst) {
  __shared__ float As[32][33];
  __shared__ float Bs[32][41];
  int tid = threadIdx.x;
  int row0 = blockIdx.x * 32;
  int ty = tid >> 3;
  int tx = tid & 7;
  float acc[5] = {};
  for (int k0 = 0; k0 < D1; k0 += 32) {
    int l = tid * 4;
    int am = l >> 5, ak = l & 31;
    int ar = row0 + am;
    float4 av = (ar < N_NODES) ? *(const float4*)&A[(size_t)ar * D1 + k0 + ak]
                               : make_float4(0.f, 0.f, 0.f, 0.f);
    As[ak + 0][am] = av.x; As[ak + 1][am] = av.y; As[ak + 2][am] = av.z; As[ak + 3][am] = av.w;
#pragma unroll
    for (int i = 0; i < 5; ++i) {
      int ll = tid * 5 + i;
      int bk = ll / NCLS, bn = ll % NCLS;
      Bs[bk][bn] = B[(size_t)(k0 + bk) * NCLS + bn];
    }
    __syncthreads();
#pragma unroll
    for (int k = 0; k < 32; ++k) {
      float a = As[k][ty];
#pragma unroll
      for (int j = 0; j < 5; ++j) acc[j] += a * Bs[k][tx * 5 + j];
    }
    __syncthreads();
  }
  int r = row0 + ty;
  float asv[5], adv[5];
#pragma unroll
  for (int j = 0; j < 5; ++j) { asv[j] = a_src[tx * 5 + j]; adv[j] = a_dst[tx * 5 + j]; }
  float ps = 0.f, pd = 0.f;
#pragma unroll
  for (int j = 0; j < 5; ++j) { ps += acc[j] * asv[j]; pd += acc[j] * adv[j]; }
#pragma unroll
  for (int o = 4; o > 0; o >>= 1) { ps += __shfl_xor(ps, o); pd += __shfl_xor(pd, o); }
  if (r < N_NODES) {
#pragma unroll
    for (int j = 0; j < 5; ++j) C[(size_t)r * NCLS + tx * 5 + j] = acc[j];
    if (tx == 0) { asrc[r] = ps; adst[r] = pd; }
  }
}

// ---------------- agg2: LDS alpha + b2 + log_softmax -> d_out ----------------
__global__ __launch_bounds__(256) void agg2_kernel(const int* __restrict__ offsets,
                                                   const int* __restrict__ edge_src,
                                                   const float* __restrict__ asrc,
                                                   const float* __restrict__ adst,
                                                   const float* __restrict__ h2,
                                                   const float* __restrict__ b2,
                                                   float* __restrict__ out) {
  __shared__ float lalpha[4][MAXD + 1];
  __shared__ int   lsoff[4][MAXD + 1];
  int w = threadIdx.x >> 6;
  int lane = threadIdx.x & 63;
  int n = blockIdx.x * 4 + w;   // grid = 5000 exactly, no remainder
  int base = offsets[n];
  int deg = offsets[n + 1] - base;
  int degc = min(deg, MAXD);

  float advv = adst[n];
  // phase 0 + pass A (lane-strided; e==lane for deg<=64 so same-lane LDS reuse)
  float m = -INFINITY;
  for (int e = lane; e < deg; e += 64) {
    int s = edge_src[base + e];
    float ev = lrelu(asrc[s] + advv);
    if (e < MAXD) { lsoff[w][e] = s * (NCLS * 4); lalpha[w][e] = ev; }
    m = fmaxf(m, ev);
  }
  m = wave_max(m);
  float ssum = 0.f;
  for (int e = lane; e < deg; e += 64) {
    float ev;
    if (e < MAXD) ev = lalpha[w][e];
    else { int s = edge_src[base + e]; ev = lrelu(asrc[s] + advv); }
    ssum += __expf(ev - m);
  }
  float inv = 1.f / (wave_sum(ssum) + 1e-16f);
  for (int e = lane; e < degc; e += 64) lalpha[w][e] = __expf(lalpha[w][e] - m) * inv;
  __syncthreads();

  float acc = 0.f;
  const char* hb = (const char*)h2 + (lane < NCLS ? lane * 4 : 0);
  for (int e = 0; e < degc; ++e) {
    float a = lalpha[w][e];
    int so = lsoff[w][e];
    float hv = *(const float*)(hb + so);
    if (lane < NCLS) acc += a * hv;
  }
  for (int e = MAXD; e < deg; ++e) {
    int s = edge_src[base + e];
    float a = __expf(lrelu(asrc[s] + advv) - m) * inv;
    if (lane < NCLS) acc += a * h2[(size_t)s * NCLS + lane];
  }
  float v = (lane < NCLS) ? acc + b2[lane] : -INFINITY;
  float m2 = wave_max(v);
  float se = wave_sum((lane < NCLS) ? __expf(v - m2) : 0.f);
  if (lane < NCLS) out[(size_t)n * NCLS + lane] = v - m2 - logf(se);
}

extern "C" void kernel_launch(void* const* d_in, const int* in_sizes, int n_in,
                              void* d_out, int out_size, void* d_ws, size_t ws_size,
                              hipStream_t stream) {
  const float* x   = (const float*)d_in[0];
  const int*   ei  = (const int*)d_in[1];
  const float* W1  = (const float*)d_in[2];
  const float* as1 = (const float*)d_in[3];
  const float* ad1 = (const float*)d_in[4];
  const float* b1  = (const float*)d_in[5];
  const float* W2  = (const float*)d_in[6];
  const float* as2 = (const float*)d_in[7];
  const float* ad2 = (const float*)d_in[8];
  const float* b2  = (const float*)d_in[9];
  float* out = (float*)d_out;

  char* ws = (char*)d_ws;
  size_t off = 0;
  auto alloc = [&](size_t bytes) -> char* {
    char* p = ws + off;
    off += (bytes + 255) & ~(size_t)255;
    return p;
  };
  int* deg      = (int*)alloc((size_t)N_NODES * 4);
  int* cursor   = (int*)alloc((size_t)N_NODES * 4);
  int* offsets  = (int*)alloc((size_t)(N_NODES + 1) * 4);
  int* edge_src = (int*)alloc((size_t)EP * 4);
  unsigned short* h1b = (unsigned short*)alloc((size_t)N_NODES * D1 * 2);
  float* out1   = (float*)alloc((size_t)N_NODES * D1 * 4);
  float* asrc1  = (float*)alloc((size_t)N_NODES * H1 * 4);
  float* adst1  = (float*)alloc((size_t)N_NODES * H1 * 4);
  float* h2     = (float*)alloc((size_t)N_NODES * NCLS * 4);
  float* asrc2  = (float*)alloc((size_t)N_NODES * 4);
  float* adst2  = (float*)alloc((size_t)N_NODES * 4);

  hipMemsetAsync(deg, 0, (size_t)N_NODES * 4, stream);
  hipMemsetAsync(cursor, 0, (size_t)N_NODES * 4, stream);

  count_deg<<<(EP + 255) / 256, 256, 0, stream>>>(ei, deg);
  scan_kernel<<<1, SCAN_T, 0, stream>>>(deg, offsets);
  scatter_edges<<<(EP + 255) / 256, 256, 0, stream>>>(ei, offsets, cursor, edge_src);

  gemm1_kernel<<<313 * 8, 256, 0, stream>>>(x, W1, as1, ad1, h1b, asrc1, adst1);
  agg1_kernel<<<N_NODES, 512, 0, stream>>>(offsets, edge_src, asrc1, adst1, h1b, b1, out1);

  gemm2_kernel<<<(N_NODES + 31) / 32, 256, 0, stream>>>(out1, W2, as2, ad2, h2, asrc2, adst2);
  agg2_kernel<<<N_NODES / 4, 256, 0, stream>>>(offsets, edge_src, asrc2, adst2, h2, b2, out);
}

// Round 3
// 229.310 us; speedup vs baseline: 2.0913x; 1.4863x over previous
//
#include <hip/hip_runtime.h>
#include <hip/hip_bf16.h>
#include <math.h>

#define N_NODES 20000
#define MPAD 20096               // 157*128
#define N_EDGES 320000
#define EP (N_EDGES + N_NODES)   // 340000
#define F_IN 256
#define NHID 64
#define H1 8
#define D1 512
#define NCLS 40
#define NEG_SLOPE 0.2f
#define MAXD 64

typedef __attribute__((ext_vector_type(8))) short bf16x8;
typedef __attribute__((ext_vector_type(4))) float f32x4;

__device__ __forceinline__ float wave_max(float v) {
#pragma unroll
  for (int o = 32; o > 0; o >>= 1) v = fmaxf(v, __shfl_xor(v, o));
  return v;
}
__device__ __forceinline__ float wave_sum(float v) {
#pragma unroll
  for (int o = 32; o > 0; o >>= 1) v += __shfl_xor(v, o);
  return v;
}
__device__ __forceinline__ float bf2f(unsigned short u) {
  union { unsigned int i; float f; } c; c.i = ((unsigned int)u) << 16; return c.f;
}
__device__ __forceinline__ unsigned short f2bf(float f) {
  union { float f; unsigned int i; } c; c.f = f;
  unsigned int x = c.i;
  return (unsigned short)((x + 0x7fffu + ((x >> 16) & 1u)) >> 16);  // RNE
}
__device__ __forceinline__ float lrelu(float x) { return x > 0.f ? x : NEG_SLOPE * x; }

// async global->LDS, 16B per lane; LDS dest = wave-uniform base + lane*16
__device__ __forceinline__ void gload16(const void* g, void* l) {
  __builtin_amdgcn_global_load_lds((const __attribute__((address_space(1))) void*)g,
                                   (__attribute__((address_space(3))) void*)l, 16, 0, 0);
}

// ---------------- CSR build ----------------
__global__ void count_deg(const int* __restrict__ ei, int* __restrict__ deg) {
  int e = blockIdx.x * blockDim.x + threadIdx.x;
  if (e >= EP) return;
  int dst = (e < N_EDGES) ? ei[N_EDGES + e] : (e - N_EDGES);
  atomicAdd(&deg[dst], 1);
}

#define SCAN_T 256
#define SCAN_CHUNK 79
__global__ void scan_kernel(const int* __restrict__ deg, int* __restrict__ offsets) {
  __shared__ int sums[SCAN_T];
  int t = threadIdx.x;
  int lo = t * SCAN_CHUNK;
  int hi = min(lo + SCAN_CHUNK, N_NODES);
  int s = 0;
  for (int i = lo; i < hi; ++i) s += deg[i];
  sums[t] = s;
  __syncthreads();
  if (t == 0) {
    int run = 0;
    for (int i = 0; i < SCAN_T; ++i) { int v = sums[i]; sums[i] = run; run += v; }
  }
  __syncthreads();
  int run = sums[t];
  for (int i = lo; i < hi; ++i) { offsets[i] = run; run += deg[i]; }
  if (hi == N_NODES) offsets[N_NODES] = run;
}

__global__ void scatter_edges(const int* __restrict__ ei, const int* __restrict__ offsets,
                              int* __restrict__ cursor, int* __restrict__ edge_src) {
  int e = blockIdx.x * blockDim.x + threadIdx.x;
  if (e >= EP) return;
  int src, dst;
  if (e < N_EDGES) { src = ei[e]; dst = ei[N_EDGES + e]; }
  else             { src = dst = e - N_EDGES; }
  int pos = offsets[dst] + atomicAdd(&cursor[dst], 1);
  edge_src[pos] = src;
}

// ---------------- converts ----------------
__global__ void convert_x(const float* __restrict__ x, unsigned short* __restrict__ xb) {
  size_t base = ((size_t)blockIdx.x * blockDim.x + threadIdx.x) * 8;
  int row = (int)(base >> 8);
  ushort4 o0, o1;
  if (row < N_NODES) {
    float4 v0 = *(const float4*)&x[base];
    float4 v1 = *(const float4*)&x[base + 4];
    o0 = make_ushort4(f2bf(v0.x), f2bf(v0.y), f2bf(v0.z), f2bf(v0.w));
    o1 = make_ushort4(f2bf(v1.x), f2bf(v1.y), f2bf(v1.z), f2bf(v1.w));
  } else {
    o0 = make_ushort4(0, 0, 0, 0); o1 = o0;
  }
  *(ushort4*)&xb[base] = o0;
  *(ushort4*)&xb[base + 4] = o1;
}

// W1 [256][512] f32 -> wb1t [512][256] bf16 (transposed)
__global__ __launch_bounds__(256) void transpose_w1(const float* __restrict__ W1,
                                                    unsigned short* __restrict__ wb1t) {
  __shared__ float t[64][65];
  int bk = blockIdx.x & 3, bn = blockIdx.x >> 2;
  int tr = threadIdx.x >> 4, tc4 = (threadIdx.x & 15) * 4;
#pragma unroll
  for (int i = 0; i < 4; ++i) {
    int k = i * 16 + tr;
    float4 v = *(const float4*)&W1[(size_t)(bk * 64 + k) * D1 + bn * 64 + tc4];
    t[k][tc4] = v.x; t[k][tc4 + 1] = v.y; t[k][tc4 + 2] = v.z; t[k][tc4 + 3] = v.w;
  }
  __syncthreads();
#pragma unroll
  for (int i = 0; i < 4; ++i) {
    int n = i * 16 + tr;
    ushort4 o = make_ushort4(f2bf(t[tc4][n]), f2bf(t[tc4 + 1][n]),
                             f2bf(t[tc4 + 2][n]), f2bf(t[tc4 + 3][n]));
    *(ushort4*)&wb1t[(size_t)(bn * 64 + n) * F_IN + bk * 64 + tc4] = o;
  }
}

// W2 [512][40] f32 -> wb2t [48][512] bf16 (transposed, zero-padded cols 40..47)
__global__ void transpose_w2(const float* __restrict__ W2, unsigned short* __restrict__ wb2t) {
  int c = blockIdx.x;   // 0..47
  int k = threadIdx.x;  // 0..511
  float v = (c < NCLS) ? W2[(size_t)k * NCLS + c] : 0.f;
  wb2t[(size_t)c * D1 + k] = f2bf(v);
}

// ---------------- GEMM1 (MFMA): h1b = xb @ W1, fused alpha1 ----------------
// grid = 157*4, block 256 (4 waves, each 64x64). BK=32.
__global__ __launch_bounds__(256) void gemm1_mfma(const unsigned short* __restrict__ xb,
                                                  const unsigned short* __restrict__ wb1t,
                                                  const float* __restrict__ a_src,
                                                  const float* __restrict__ a_dst,
                                                  unsigned short* __restrict__ h1b,
                                                  float* __restrict__ asrc,
                                                  float* __restrict__ adst) {
  __shared__ unsigned short As[128 * 32];
  __shared__ unsigned short Bs[128 * 32];
  int tid = threadIdx.x;
  int w = tid >> 6, lane = tid & 63;
  int bn = blockIdx.x & 3, bm = blockIdx.x >> 2;
  int row0 = bm * 128, col0 = bn * 128;
  int wr = w >> 1, wc = w & 1;
  int cl = lane & 15, hi = lane >> 4;
  f32x4 acc[4][4] = {};
  for (int k0 = 0; k0 < F_IN; k0 += 32) {
#pragma unroll
    for (int c = 0; c < 2; ++c) {
      int slot = c * 256 + tid;
      int r = slot >> 2;
      int q = (slot & 3) ^ ((slot >> 3) & 3);   // pre-swizzled source (rule 21)
      gload16(xb + (size_t)(row0 + r) * F_IN + k0 + q * 8, (char*)As + (c * 256 + w * 64) * 16);
      gload16(wb1t + (size_t)(col0 + r) * F_IN + k0 + q * 8, (char*)Bs + (c * 256 + w * 64) * 16);
    }
    __syncthreads();   // compiler drains vmcnt before barrier
    bf16x8 a[4], b[4];
#pragma unroll
    for (int m = 0; m < 4; ++m) {
      int r = wr * 64 + m * 16 + cl;
      a[m] = *(const bf16x8*)&As[r * 32 + ((hi ^ ((r >> 1) & 3)) << 3)];
    }
#pragma unroll
    for (int n = 0; n < 4; ++n) {
      int r = wc * 64 + n * 16 + cl;
      b[n] = *(const bf16x8*)&Bs[r * 32 + ((hi ^ ((r >> 1) & 3)) << 3)];
    }
#pragma unroll
    for (int m = 0; m < 4; ++m)
#pragma unroll
      for (int n = 0; n < 4; ++n)
        acc[m][n] = __builtin_amdgcn_mfma_f32_16x16x32_bf16(a[m], b[n], acc[m][n], 0, 0, 0);
    __syncthreads();
  }
  // epilogue: bf16 store + fused per-head alpha (wave's 64 cols == one head)
  int head = bn * 2 + wc;
  float asv[4], adv[4];
#pragma unroll
  for (int n = 0; n < 4; ++n) {
    asv[n] = a_src[head * 64 + n * 16 + cl];
    adv[n] = a_dst[head * 64 + n * 16 + cl];
  }
#pragma unroll
  for (int m = 0; m < 4; ++m) {
#pragma unroll
    for (int r = 0; r < 4; ++r) {
      int grow = row0 + wr * 64 + m * 16 + hi * 4 + r;
      float ps = acc[m][0][r] * asv[0] + acc[m][1][r] * asv[1] +
                 acc[m][2][r] * asv[2] + acc[m][3][r] * asv[3];
      float pd = acc[m][0][r] * adv[0] + acc[m][1][r] * adv[1] +
                 acc[m][2][r] * adv[2] + acc[m][3][r] * adv[3];
#pragma unroll
      for (int o = 8; o > 0; o >>= 1) { ps += __shfl_xor(ps, o); pd += __shfl_xor(pd, o); }
      if (grow < N_NODES) {
#pragma unroll
        for (int n = 0; n < 4; ++n)
          h1b[(size_t)grow * D1 + col0 + wc * 64 + n * 16 + cl] = f2bf(acc[m][n][r]);
        if (cl == 0) { asrc[grow * H1 + head] = ps; adst[grow * H1 + head] = pd; }
      }
    }
  }
}

// ---------------- agg1: LDS alpha + bf16 gather + b1 + ELU -> bf16 out1 ----------------
__global__ __launch_bounds__(512) void agg1_kernel(const int* __restrict__ offsets,
                                                   const int* __restrict__ edge_src,
                                                   const float* __restrict__ asrc,
                                                   const float* __restrict__ adst,
                                                   const unsigned short* __restrict__ h1b,
                                                   const float* __restrict__ b1,
                                                   unsigned short* __restrict__ out1b) {
  __shared__ float lalpha[H1][MAXD + 2];
  __shared__ int   lsoff[MAXD + 2];
  int n = blockIdx.x;
  int h = threadIdx.x >> 6;
  int lane = threadIdx.x & 63;
  int base = offsets[n];
  int deg = offsets[n + 1] - base;
  int degc = min(deg, MAXD);

  for (int e = (int)threadIdx.x; e < degc; e += 512) lsoff[e] = edge_src[base + e] << 10;
  if (threadIdx.x == 0 && (degc & 1)) lsoff[degc] = 0;
  __syncthreads();

  float advv = adst[n * H1 + h];
  float m = -INFINITY;
  for (int e = lane; e < deg; e += 64) {
    int s = (e < MAXD) ? (lsoff[e] >> 10) : edge_src[base + e];
    float ev = lrelu(asrc[s * H1 + h] + advv);
    if (e < MAXD) lalpha[h][e] = ev;
    m = fmaxf(m, ev);
  }
  m = wave_max(m);
  float ssum = 0.f;
  for (int e = lane; e < deg; e += 64) {
    float ev;
    if (e < MAXD) ev = lalpha[h][e];
    else { int s = edge_src[base + e]; ev = lrelu(asrc[s * H1 + h] + advv); }
    ssum += __expf(ev - m);
  }
  float inv = 1.f / (wave_sum(ssum) + 1e-16f);
  for (int e = lane; e < degc; e += 64) lalpha[h][e] = __expf(lalpha[h][e] - m) * inv;
  if (lane == 0 && (degc & 1)) lalpha[h][degc] = 0.f;
  __syncthreads();

  int half = lane >> 5;
  int fl = lane & 31;
  const char* hb = (const char*)h1b + h * 128 + fl * 4;
  float ax = 0.f, ay = 0.f;
  int ngrp = (degc + 1) >> 1;
  for (int i = 0; i < ngrp; ++i) {
    int slot = 2 * i + half;
    float a = lalpha[h][slot];
    int so = lsoff[slot];
    unsigned int uv = *(const unsigned int*)(hb + so);
    ax += a * bf2f((unsigned short)(uv & 0xffffu));
    ay += a * bf2f((unsigned short)(uv >> 16));
  }
  for (int e = MAXD + half; e < deg; e += 2) {
    int s = edge_src[base + e];
    float a = __expf(lrelu(asrc[s * H1 + h] + advv) - m) * inv;
    unsigned int uv = *(const unsigned int*)(hb + ((size_t)s << 10));
    ax += a * bf2f((unsigned short)(uv & 0xffffu));
    ay += a * bf2f((unsigned short)(uv >> 16));
  }
  ax += __shfl_xor(ax, 32);
  ay += __shfl_xor(ay, 32);
  if (half == 0) {
    int c = h * NHID + fl * 2;
    float vx = ax + b1[c], vy = ay + b1[c + 1];
    vx = vx > 0.f ? vx : (__expf(vx) - 1.f);
    vy = vy > 0.f ? vy : (__expf(vy) - 1.f);
    ushort2 o; o.x = f2bf(vx); o.y = f2bf(vy);
    *(ushort2*)&out1b[(size_t)n * D1 + c] = o;
  }
}

// ---------------- GEMM2 (MFMA): h2 = out1b @ W2 (+pad), fused alpha2 ----------------
// grid = 157, block 256 (4 waves, each 32x48). BK=32, 16 K-steps.
__global__ __launch_bounds__(256) void gemm2_mfma(const unsigned short* __restrict__ ab,
                                                  const unsigned short* __restrict__ wb2t,
                                                  const float* __restrict__ a_src2,
                                                  const float* __restrict__ a_dst2,
                                                  float* __restrict__ h2,
                                                  float* __restrict__ asrc,
                                                  float* __restrict__ adst) {
  __shared__ unsigned short As[128 * 32];
  __shared__ unsigned short Bs[48 * 32];
  int tid = threadIdx.x;
  int w = tid >> 6, lane = tid & 63;
  int row0 = blockIdx.x * 128;
  int cl = lane & 15, hi = lane >> 4;
  f32x4 acc[2][3] = {};
  for (int k0 = 0; k0 < D1; k0 += 32) {
#pragma unroll
    for (int c = 0; c < 2; ++c) {
      int slot = c * 256 + tid;
      int r = slot >> 2;
      int q = (slot & 3) ^ ((slot >> 3) & 3);
      gload16(ab + (size_t)(row0 + r) * D1 + k0 + q * 8, (char*)As + (c * 256 + w * 64) * 16);
    }
    if (tid < 192) {
      int r = tid >> 2;
      int q = (tid & 3) ^ ((tid >> 3) & 3);
      gload16(wb2t + (size_t)r * D1 + k0 + q * 8, (char*)Bs + w * 64 * 16);
    }
    __syncthreads();
    bf16x8 a[2], b[3];
#pragma unroll
    for (int m = 0; m < 2; ++m) {
      int r = w * 32 + m * 16 + cl;
      a[m] = *(const bf16x8*)&As[r * 32 + ((hi ^ ((r >> 1) & 3)) << 3)];
    }
#pragma unroll
    for (int n = 0; n < 3; ++n) {
      int r = n * 16 + cl;
      b[n] = *(const bf16x8*)&Bs[r * 32 + ((hi ^ ((r >> 1) & 3)) << 3)];
    }
#pragma unroll
    for (int m = 0; m < 2; ++m)
#pragma unroll
      for (int n = 0; n < 3; ++n)
        acc[m][n] = __builtin_amdgcn_mfma_f32_16x16x32_bf16(a[m], b[n], acc[m][n], 0, 0, 0);
    __syncthreads();
  }
  float asv[3], adv[3];
#pragma unroll
  for (int n = 0; n < 3; ++n) {
    int c = n * 16 + cl;
    asv[n] = (c < NCLS) ? a_src2[c] : 0.f;
    adv[n] = (c < NCLS) ? a_dst2[c] : 0.f;
  }
#pragma unroll
  for (int m = 0; m < 2; ++m) {
#pragma unroll
    for (int r = 0; r < 4; ++r) {
      int grow = row0 + w * 32 + m * 16 + hi * 4 + r;
      float ps = acc[m][0][r] * asv[0] + acc[m][1][r] * asv[1] + acc[m][2][r] * asv[2];
      float pd = acc[m][0][r] * adv[0] + acc[m][1][r] * adv[1] + acc[m][2][r] * adv[2];
#pragma unroll
      for (int o = 8; o > 0; o >>= 1) { ps += __shfl_xor(ps, o); pd += __shfl_xor(pd, o); }
      if (grow < N_NODES) {
#pragma unroll
        for (int n = 0; n < 3; ++n) {
          int c = n * 16 + cl;
          if (c < NCLS) h2[(size_t)grow * NCLS + c] = acc[m][n][r];
        }
        if (cl == 0) { asrc[grow] = ps; adst[grow] = pd; }
      }
    }
  }
}

// ---------------- agg2: LDS alpha + b2 + log_softmax -> d_out ----------------
__global__ __launch_bounds__(256) void agg2_kernel(const int* __restrict__ offsets,
                                                   const int* __restrict__ edge_src,
                                                   const float* __restrict__ asrc,
                                                   const float* __restrict__ adst,
                                                   const float* __restrict__ h2,
                                                   const float* __restrict__ b2,
                                                   float* __restrict__ out) {
  __shared__ float lalpha[4][MAXD + 1];
  __shared__ int   lsoff[4][MAXD + 1];
  int w = threadIdx.x >> 6;
  int lane = threadIdx.x & 63;
  int n = blockIdx.x * 4 + w;
  int base = offsets[n];
  int deg = offsets[n + 1] - base;
  int degc = min(deg, MAXD);

  float advv = adst[n];
  float m = -INFINITY;
  for (int e = lane; e < deg; e += 64) {
    int s = edge_src[base + e];
    float ev = lrelu(asrc[s] + advv);
    if (e < MAXD) { lsoff[w][e] = s * (NCLS * 4); lalpha[w][e] = ev; }
    m = fmaxf(m, ev);
  }
  m = wave_max(m);
  float ssum = 0.f;
  for (int e = lane; e < deg; e += 64) {
    float ev;
    if (e < MAXD) ev = lalpha[w][e];
    else { int s = edge_src[base + e]; ev = lrelu(asrc[s] + advv); }
    ssum += __expf(ev - m);
  }
  float inv = 1.f / (wave_sum(ssum) + 1e-16f);
  for (int e = lane; e < degc; e += 64) lalpha[w][e] = __expf(lalpha[w][e] - m) * inv;
  __syncthreads();

  float acc = 0.f;
  const char* hb = (const char*)h2 + (lane < NCLS ? lane * 4 : 0);
  for (int e = 0; e < degc; ++e) {
    float a = lalpha[w][e];
    int so = lsoff[w][e];
    float hv = *(const float*)(hb + so);
    if (lane < NCLS) acc += a * hv;
  }
  for (int e = MAXD; e < deg; ++e) {
    int s = edge_src[base + e];
    float a = __expf(lrelu(asrc[s] + advv) - m) * inv;
    if (lane < NCLS) acc += a * h2[(size_t)s * NCLS + lane];
  }
  float v = (lane < NCLS) ? acc + b2[lane] : -INFINITY;
  float m2 = wave_max(v);
  float se = wave_sum((lane < NCLS) ? __expf(v - m2) : 0.f);
  if (lane < NCLS) out[(size_t)n * NCLS + lane] = v - m2 - logf(se);
}

extern "C" void kernel_launch(void* const* d_in, const int* in_sizes, int n_in,
                              void* d_out, int out_size, void* d_ws, size_t ws_size,
                              hipStream_t stream) {
  const float* x   = (const float*)d_in[0];
  const int*   ei  = (const int*)d_in[1];
  const float* W1  = (const float*)d_in[2];
  const float* as1 = (const float*)d_in[3];
  const float* ad1 = (const float*)d_in[4];
  const float* b1  = (const float*)d_in[5];
  const float* W2  = (const float*)d_in[6];
  const float* as2 = (const float*)d_in[7];
  const float* ad2 = (const float*)d_in[8];
  const float* b2  = (const float*)d_in[9];
  float* out = (float*)d_out;

  char* ws = (char*)d_ws;
  size_t off = 0;
  auto alloc = [&](size_t bytes) -> char* {
    char* p = ws + off;
    off += (bytes + 255) & ~(size_t)255;
    return p;
  };
  int* deg      = (int*)alloc((size_t)N_NODES * 4);
  int* cursor   = (int*)alloc((size_t)N_NODES * 4);
  int* offsets  = (int*)alloc((size_t)(N_NODES + 1) * 4);
  int* edge_src = (int*)alloc((size_t)EP * 4);
  unsigned short* xb    = (unsigned short*)alloc((size_t)MPAD * F_IN * 2);
  unsigned short* wb1t  = (unsigned short*)alloc((size_t)D1 * F_IN * 2);
  unsigned short* wb2t  = (unsigned short*)alloc((size_t)48 * D1 * 2);
  unsigned short* h1b   = (unsigned short*)alloc((size_t)N_NODES * D1 * 2);
  unsigned short* out1b = (unsigned short*)alloc((size_t)MPAD * D1 * 2);
  float* asrc1  = (float*)alloc((size_t)N_NODES * H1 * 4);
  float* adst1  = (float*)alloc((size_t)N_NODES * H1 * 4);
  float* h2     = (float*)alloc((size_t)N_NODES * NCLS * 4);
  float* asrc2  = (float*)alloc((size_t)N_NODES * 4);
  float* adst2  = (float*)alloc((size_t)N_NODES * 4);

  hipMemsetAsync(deg, 0, (size_t)N_NODES * 4, stream);
  hipMemsetAsync(cursor, 0, (size_t)N_NODES * 4, stream);
  hipMemsetAsync(out1b + (size_t)N_NODES * D1, 0, (size_t)(MPAD - N_NODES) * D1 * 2, stream);

  convert_x<<<(MPAD * F_IN / 8 + 255) / 256, 256, 0, stream>>>(x, xb);
  transpose_w1<<<32, 256, 0, stream>>>(W1, wb1t);
  transpose_w2<<<48, 512, 0, stream>>>(W2, wb2t);

  count_deg<<<(EP + 255) / 256, 256, 0, stream>>>(ei, deg);
  scan_kernel<<<1, SCAN_T, 0, stream>>>(deg, offsets);
  scatter_edges<<<(EP + 255) / 256, 256, 0, stream>>>(ei, offsets, cursor, edge_src);

  gemm1_mfma<<<157 * 4, 256, 0, stream>>>(xb, wb1t, as1, ad1, h1b, asrc1, adst1);
  agg1_kernel<<<N_NODES, 512, 0, stream>>>(offsets, edge_src, asrc1, adst1, h1b, b1, out1b);

  gemm2_mfma<<<157, 256, 0, stream>>>(out1b, wb2t, as2, ad2, h2, asrc2, adst2);
  agg2_kernel<<<N_NODES / 4, 256, 0, stream>>>(offsets, edge_src, asrc2, adst2, h2, b2, out);
}